// Round 5
// baseline (174.662 us; speedup 1.0000x reference)
//
#include <hip/hip_runtime.h>

#define DF 256   // feature dim
#define CH 64    // nodes per wave-chunk (N % 64 == 0 for N=200000)

// ---- 1. histogram ----
__global__ void cp_count(const int* __restrict__ cmap, int* __restrict__ counts, int n) {
    int i = blockIdx.x * blockDim.x + threadIdx.x;
    if (i < n) atomicAdd(&counts[cmap[i]], 1);
}

// ---- 2a. per-block exclusive scan ----
__global__ void cp_scanA(const int* __restrict__ counts, int* __restrict__ offsets,
                         int* __restrict__ blocksums, int C) {
    __shared__ int s[256];
    int tid = threadIdx.x;
    int i = blockIdx.x * 256 + tid;
    int v = (i < C) ? counts[i] : 0;
    s[tid] = v;
    __syncthreads();
    for (int off = 1; off < 256; off <<= 1) {
        int t = (tid >= off) ? s[tid - off] : 0;
        __syncthreads();
        s[tid] += t;
        __syncthreads();
    }
    if (i < C) offsets[i] = s[tid] - v;
    if (tid == 255) blocksums[blockIdx.x] = s[255];
}

// ---- 2b. scan block sums ----
__global__ void cp_scanB(int* __restrict__ blocksums, int nb) {
    __shared__ int s[256];
    int tid = threadIdx.x;
    if (nb <= 256) {
        int v = (tid < nb) ? blocksums[tid] : 0;
        s[tid] = v;
        __syncthreads();
        for (int off = 1; off < 256; off <<= 1) {
            int t = (tid >= off) ? s[tid - off] : 0;
            __syncthreads();
            s[tid] += t;
            __syncthreads();
        }
        if (tid < nb) blocksums[tid] = s[tid] - v;
    } else if (tid == 0) {
        int run = 0;
        for (int k = 0; k < nb; ++k) { int t = blocksums[k]; blocksums[k] = run; run += t; }
    }
}

// ---- 2c. finalize offsets; build seg[c]={start,len}; init cursor=offsets ----
__global__ void cp_scanC(int* __restrict__ offsets, const int* __restrict__ blocksums,
                         const int* __restrict__ counts, int2* __restrict__ seg,
                         int* __restrict__ cursor, int C) {
    int i = blockIdx.x * 256 + threadIdx.x;
    if (i < C) {
        int st = offsets[i] + blocksums[blockIdx.x];
        offsets[i] = st;
        cursor[i] = st;
        seg[i] = make_int2(st, counts[i]);
    }
}

// ---- 3. bucket-fill ----
__global__ void cp_fill(const int* __restrict__ cmap, int* __restrict__ cursor,
                        int* __restrict__ node_list, int n) {
    int i = blockIdx.x * blockDim.x + threadIdx.x;
    if (i < n) {
        int pos = atomicAdd(&cursor[cmap[i]], 1);
        node_list[pos] = i;
    }
}

// ---- 3b. pre-zero rows of edge-spanning and empty clusters ----
__global__ void cp_prep(const int2* __restrict__ seg, float* __restrict__ xp,
                        float* __restrict__ hp, int C) {
    int c = blockIdx.x * 4 + (threadIdx.x >> 6);
    if (c >= C) return;
    int lane = threadIdx.x & 63;
    int2 s = seg[c];
    bool empty = (s.y == 0);
    bool edge  = !empty && ((s.x >> 6) != ((s.x + s.y - 1) >> 6));
    if (empty || edge) {
        float4 z = make_float4(0.f, 0.f, 0.f, 0.f);
        reinterpret_cast<float4*>(xp + (size_t)c * DF)[lane] = z;
        reinterpret_cast<float4*>(hp + (size_t)c * DF)[lane] = z;
    }
}

// ---- 4. pool: balanced segmented reduction, 64 node_list slots per wave ----
__global__ void __launch_bounds__(256) cp_pool(
        const float* __restrict__ x, const float* __restrict__ h,
        const int* __restrict__ cmap,
        const int2* __restrict__ seg, const int* __restrict__ node_list,
        float* __restrict__ xp, float* __restrict__ hp, int n_nodes) {
    int gw   = (blockIdx.x * blockDim.x + threadIdx.x) >> 6;
    int lane = threadIdx.x & 63;
    int base = gw * CH;
    if (base >= n_nodes) return;

    // per-lane metadata for node_list position base+lane
    int p = base + lane;
    int nid_l = 0, cid_l = 0;
    int2 seg_l = make_int2(0, 0);
    if (p < n_nodes) {
        nid_l = node_list[p];
        cid_l = cmap[nid_l];
        seg_l = seg[cid_l];
    }
    int kend = n_nodes - base; if (kend > CH) kend = CH;

    float4 ax = make_float4(0.f,0.f,0.f,0.f), ah = make_float4(0.f,0.f,0.f,0.f);
    int cur      = __shfl(cid_l, 0);
    int curstart = __shfl(seg_l.x, 0);
    int curlen   = __shfl(seg_l.y, 0);
    int k0 = 0;

    auto flush = [&](int runend) {
        bool owned = (curstart == base + k0) && (curstart + curlen == base + runend);
        float* xrow = xp + (size_t)cur * DF + lane * 4;
        float* hrow = hp + (size_t)cur * DF + lane * 4;
        if (owned) {
            float inv = 1.0f / (float)curlen;
            float4 vx = make_float4(ax.x*inv, ax.y*inv, ax.z*inv, ax.w*inv);
            float4 vh = make_float4(ah.x*inv, ah.y*inv, ah.z*inv, ah.w*inv);
            *reinterpret_cast<float4*>(xrow) = vx;
            *reinterpret_cast<float4*>(hrow) = vh;
        } else {
            atomicAdd(xrow+0, ax.x); atomicAdd(xrow+1, ax.y);
            atomicAdd(xrow+2, ax.z); atomicAdd(xrow+3, ax.w);
            atomicAdd(hrow+0, ah.x); atomicAdd(hrow+1, ah.y);
            atomicAdd(hrow+2, ah.z); atomicAdd(hrow+3, ah.w);
        }
        ax = make_float4(0.f,0.f,0.f,0.f);
        ah = make_float4(0.f,0.f,0.f,0.f);
    };

    auto start_run = [&](int k) {
        k0 = k;
        curstart = __shfl(seg_l.x, k);
        curlen   = __shfl(seg_l.y, k);
    };

    if (kend == CH) {
        // fast path: full chunk, double-buffered groups of 4 rows
        float4 bx0[4], bh0[4], bx1[4], bh1[4];
        #pragma unroll
        for (int j = 0; j < 4; ++j) {
            int n = __shfl(nid_l, j);
            bx0[j] = reinterpret_cast<const float4*>(x + (size_t)n * DF)[lane];
            bh0[j] = reinterpret_cast<const float4*>(h + (size_t)n * DF)[lane];
        }
        for (int gg = 0; gg < 8; ++gg) {
            int g0k = gg * 8;
            // prefetch positions g0k+4..g0k+7 into buf1
            #pragma unroll
            for (int j = 0; j < 4; ++j) {
                int n = __shfl(nid_l, g0k + 4 + j);
                bx1[j] = reinterpret_cast<const float4*>(x + (size_t)n * DF)[lane];
                bh1[j] = reinterpret_cast<const float4*>(h + (size_t)n * DF)[lane];
            }
            // process buf0 (positions g0k..g0k+3)
            #pragma unroll
            for (int j = 0; j < 4; ++j) {
                int k = g0k + j;
                int c = __shfl(cid_l, k);
                if (c != cur) { flush(k); cur = c; start_run(k); }
                ax.x += bx0[j].x; ax.y += bx0[j].y; ax.z += bx0[j].z; ax.w += bx0[j].w;
                ah.x += bh0[j].x; ah.y += bh0[j].y; ah.z += bh0[j].z; ah.w += bh0[j].w;
            }
            // prefetch next iteration's buf0 (positions (gg+1)*8..+3)
            if (gg < 7) {
                #pragma unroll
                for (int j = 0; j < 4; ++j) {
                    int n = __shfl(nid_l, (gg + 1) * 8 + j);
                    bx0[j] = reinterpret_cast<const float4*>(x + (size_t)n * DF)[lane];
                    bh0[j] = reinterpret_cast<const float4*>(h + (size_t)n * DF)[lane];
                }
            }
            // process buf1 (positions g0k+4..g0k+7)
            #pragma unroll
            for (int j = 0; j < 4; ++j) {
                int k = g0k + 4 + j;
                int c = __shfl(cid_l, k);
                if (c != cur) { flush(k); cur = c; start_run(k); }
                ax.x += bx1[j].x; ax.y += bx1[j].y; ax.z += bx1[j].z; ax.w += bx1[j].w;
                ah.x += bh1[j].x; ah.y += bh1[j].y; ah.z += bh1[j].z; ah.w += bh1[j].w;
            }
        }
        flush(CH);
    } else {
        // tail path (not taken for N=200000, kept for safety)
        for (int k = 0; k < kend; ++k) {
            int n = __shfl(nid_l, k);
            int c = __shfl(cid_l, k);
            if (c != cur) { flush(k); cur = c; start_run(k); }
            float4 xv = reinterpret_cast<const float4*>(x + (size_t)n * DF)[lane];
            float4 hv = reinterpret_cast<const float4*>(h + (size_t)n * DF)[lane];
            ax.x += xv.x; ax.y += xv.y; ax.z += xv.z; ax.w += xv.w;
            ah.x += hv.x; ah.y += hv.y; ah.z += hv.z; ah.w += hv.w;
        }
        flush(kend);
    }
}

// ---- 4b. finalize: divide edge-spanning clusters' sums by len ----
__global__ void cp_fin(const int2* __restrict__ seg, float* __restrict__ xp,
                       float* __restrict__ hp, int C) {
    int c = blockIdx.x * 4 + (threadIdx.x >> 6);
    if (c >= C) return;
    int lane = threadIdx.x & 63;
    int2 s = seg[c];
    if (s.y > 0 && ((s.x >> 6) != ((s.x + s.y - 1) >> 6))) {
        float inv = 1.0f / (float)s.y;
        float4* xr = reinterpret_cast<float4*>(xp + (size_t)c * DF);
        float4* hr = reinterpret_cast<float4*>(hp + (size_t)c * DF);
        float4 v = xr[lane];
        v.x *= inv; v.y *= inv; v.z *= inv; v.w *= inv;
        xr[lane] = v;
        float4 w = hr[lane];
        w.x *= inv; w.y *= inv; w.z *= inv; w.w *= inv;
        hr[lane] = w;
    }
}

// ---- 5. pos gather ----
__global__ void cp_pos(const float* __restrict__ pos, const int* __restrict__ sidx,
                       float* __restrict__ out, int C) {
    int i = blockIdx.x * blockDim.x + threadIdx.x;
    if (i >= C) return;
    int s = sidx[i];
    out[(size_t)i * 3 + 0] = pos[(size_t)s * 3 + 0];
    out[(size_t)i * 3 + 1] = pos[(size_t)s * 3 + 1];
    out[(size_t)i * 3 + 2] = pos[(size_t)s * 3 + 2];
}

extern "C" void kernel_launch(void* const* d_in, const int* in_sizes, int n_in,
                              void* d_out, int out_size, void* d_ws, size_t ws_size,
                              hipStream_t stream) {
    const float* x    = (const float*)d_in[0];
    const float* h    = (const float*)d_in[1];
    const float* pos  = (const float*)d_in[2];
    const int*   cmap = (const int*)d_in[3];
    const int*   sidx = (const int*)d_in[4];

    const int n_nodes = in_sizes[2] / 3;
    const int C       = in_sizes[4];

    float* out  = (float*)d_out;
    float* xp   = out;
    float* hp   = out + (size_t)C * DF;
    float* pout = out + (size_t)2 * C * DF;

    // ws ints: counts[C] | cursor[C] | offsets[C] | blocksums[256] | seg[2C] | node_list[N]
    int*  counts    = (int*)d_ws;
    int*  cursor    = counts + C;
    int*  offsets   = cursor + C;
    int*  blocksums = offsets + C;
    int2* seg       = (int2*)(blocksums + 256);
    int*  node_list = (int*)(seg + C);

    hipMemsetAsync(counts, 0, (size_t)C * sizeof(int), stream);

    cp_count<<<(n_nodes + 255) / 256, 256, 0, stream>>>(cmap, counts, n_nodes);

    int nb = (C + 255) / 256;
    cp_scanA<<<nb, 256, 0, stream>>>(counts, offsets, blocksums, C);
    cp_scanB<<<1, 256, 0, stream>>>(blocksums, nb);
    cp_scanC<<<nb, 256, 0, stream>>>(offsets, blocksums, counts, seg, cursor, C);

    cp_fill<<<(n_nodes + 255) / 256, 256, 0, stream>>>(cmap, cursor, node_list, n_nodes);

    cp_prep<<<(C + 3) / 4, 256, 0, stream>>>(seg, xp, hp, C);

    int nchunks = (n_nodes + CH - 1) / CH;            // 3125 waves
    int nblocks = (nchunks + 3) / 4;                  // 4 waves per block
    cp_pool<<<nblocks, 256, 0, stream>>>(x, h, cmap, seg, node_list, xp, hp, n_nodes);

    cp_fin<<<(C + 3) / 4, 256, 0, stream>>>(seg, xp, hp, C);

    cp_pos<<<(C + 255) / 256, 256, 0, stream>>>(pos, sidx, pout, C);
}

// Round 6
// 138.691 us; speedup vs baseline: 1.2594x; 1.2594x over previous
//
#include <hip/hip_runtime.h>

#define DF 256  // feature dim

typedef float f32x4 __attribute__((ext_vector_type(4)));

// ---- 1. histogram ----
__global__ void cp_count(const int* __restrict__ cmap, int* __restrict__ counts, int n) {
    int i = blockIdx.x * blockDim.x + threadIdx.x;
    if (i < n) atomicAdd(&counts[cmap[i]], 1);
}

// ---- 2a. per-block exclusive scan ----
__global__ void cp_scanA(const int* __restrict__ counts, int* __restrict__ offsets,
                         int* __restrict__ blocksums, int C) {
    __shared__ int s[256];
    int tid = threadIdx.x;
    int i = blockIdx.x * 256 + tid;
    int v = (i < C) ? counts[i] : 0;
    s[tid] = v;
    __syncthreads();
    for (int off = 1; off < 256; off <<= 1) {
        int t = (tid >= off) ? s[tid - off] : 0;
        __syncthreads();
        s[tid] += t;
        __syncthreads();
    }
    if (i < C) offsets[i] = s[tid] - v;
    if (tid == 255) blocksums[blockIdx.x] = s[255];
}

// ---- 2b. scan block sums ----
__global__ void cp_scanB(int* __restrict__ blocksums, int nb) {
    __shared__ int s[256];
    int tid = threadIdx.x;
    if (nb <= 256) {
        int v = (tid < nb) ? blocksums[tid] : 0;
        s[tid] = v;
        __syncthreads();
        for (int off = 1; off < 256; off <<= 1) {
            int t = (tid >= off) ? s[tid - off] : 0;
            __syncthreads();
            s[tid] += t;
            __syncthreads();
        }
        if (tid < nb) blocksums[tid] = s[tid] - v;
    } else if (tid == 0) {
        int run = 0;
        for (int k = 0; k < nb; ++k) { int t = blocksums[k]; blocksums[k] = run; run += t; }
    }
}

// ---- 2c. add block offsets; also build fused seg[c] = {start, len} ----
__global__ void cp_scanC(int* __restrict__ offsets, const int* __restrict__ blocksums,
                         const int* __restrict__ counts, int2* __restrict__ seg, int C) {
    int i = blockIdx.x * 256 + threadIdx.x;
    if (i < C) {
        int st = offsets[i] + blocksums[blockIdx.x];
        offsets[i] = st;
        seg[i] = make_int2(st, counts[i]);
    }
}

// ---- 3. bucket-fill ----
__global__ void cp_fill(const int* __restrict__ cmap, const int* __restrict__ offsets,
                        int* __restrict__ cursor, int* __restrict__ node_list, int n) {
    int i = blockIdx.x * blockDim.x + threadIdx.x;
    if (i < n) {
        int c = cmap[i];
        int slot = atomicAdd(&cursor[c], 1);
        node_list[offsets[c] + slot] = i;
    }
}

// ---- 4. pool: one wave per cluster; nt stores to preserve L3 input retention ----
__global__ void cp_pool(const float* __restrict__ x, const float* __restrict__ h,
                        const int2* __restrict__ seg, const int* __restrict__ node_list,
                        float* __restrict__ xp, float* __restrict__ hp, int C) {
    int c = blockIdx.x * 4 + (threadIdx.x >> 6);
    if (c >= C) return;
    int lane = threadIdx.x & 63;
    int2 sl = seg[c];                      // one 8B load: {start, len}
    int start = sl.x, len = sl.y;

    // preload up to 64 node ids in a single coalesced vector load
    int nid = 0;
    if (lane < len) nid = node_list[start + lane];

    f32x4 ax = 0.f;
    f32x4 ah = 0.f;
    int kmax = len < 64 ? len : 64;
    int k = 0;
    for (; k + 4 <= kmax; k += 4) {
        int n0 = __shfl(nid, k);
        int n1 = __shfl(nid, k + 1);
        int n2 = __shfl(nid, k + 2);
        int n3 = __shfl(nid, k + 3);
        f32x4 x0 = reinterpret_cast<const f32x4*>(x + (size_t)n0 * DF)[lane];
        f32x4 h0 = reinterpret_cast<const f32x4*>(h + (size_t)n0 * DF)[lane];
        f32x4 x1 = reinterpret_cast<const f32x4*>(x + (size_t)n1 * DF)[lane];
        f32x4 h1 = reinterpret_cast<const f32x4*>(h + (size_t)n1 * DF)[lane];
        f32x4 x2 = reinterpret_cast<const f32x4*>(x + (size_t)n2 * DF)[lane];
        f32x4 h2 = reinterpret_cast<const f32x4*>(h + (size_t)n2 * DF)[lane];
        f32x4 x3 = reinterpret_cast<const f32x4*>(x + (size_t)n3 * DF)[lane];
        f32x4 h3 = reinterpret_cast<const f32x4*>(h + (size_t)n3 * DF)[lane];
        ax += x0 + x1 + x2 + x3;
        ah += h0 + h1 + h2 + h3;
    }
    for (; k < kmax; ++k) {
        int n0 = __shfl(nid, k);
        ax += reinterpret_cast<const f32x4*>(x + (size_t)n0 * DF)[lane];
        ah += reinterpret_cast<const f32x4*>(h + (size_t)n0 * DF)[lane];
    }
    // rare tail (len > 64): serial fallback
    for (int kk = 64; kk < len; ++kk) {
        int n0 = node_list[start + kk];
        ax += reinterpret_cast<const f32x4*>(x + (size_t)n0 * DF)[lane];
        ah += reinterpret_cast<const f32x4*>(h + (size_t)n0 * DF)[lane];
    }

    float inv = 1.0f / (float)(len > 0 ? len : 1);
    f32x4 vx = ax * inv;
    f32x4 vh = ah * inv;
    __builtin_nontemporal_store(vx, reinterpret_cast<f32x4*>(xp + (size_t)c * DF) + lane);
    __builtin_nontemporal_store(vh, reinterpret_cast<f32x4*>(hp + (size_t)c * DF) + lane);
}

// ---- 5. pos gather ----
__global__ void cp_pos(const float* __restrict__ pos, const int* __restrict__ sidx,
                       float* __restrict__ out, int C) {
    int i = blockIdx.x * blockDim.x + threadIdx.x;
    if (i >= C) return;
    int s = sidx[i];
    float p0 = pos[(size_t)s * 3 + 0];
    float p1 = pos[(size_t)s * 3 + 1];
    float p2 = pos[(size_t)s * 3 + 2];
    __builtin_nontemporal_store(p0, &out[(size_t)i * 3 + 0]);
    __builtin_nontemporal_store(p1, &out[(size_t)i * 3 + 1]);
    __builtin_nontemporal_store(p2, &out[(size_t)i * 3 + 2]);
}

extern "C" void kernel_launch(void* const* d_in, const int* in_sizes, int n_in,
                              void* d_out, int out_size, void* d_ws, size_t ws_size,
                              hipStream_t stream) {
    const float* x    = (const float*)d_in[0];
    const float* h    = (const float*)d_in[1];
    const float* pos  = (const float*)d_in[2];
    const int*   cmap = (const int*)d_in[3];
    const int*   sidx = (const int*)d_in[4];

    const int n_nodes = in_sizes[2] / 3;
    const int C       = in_sizes[4];

    float* out  = (float*)d_out;
    float* xp   = out;
    float* hp   = out + (size_t)C * DF;
    float* pout = out + (size_t)2 * C * DF;

    // ws ints: counts[C] | cursor[C] | offsets[C] | blocksums[256] | seg[2C] | node_list[N]
    int*  counts    = (int*)d_ws;
    int*  cursor    = counts + C;
    int*  offsets   = cursor + C;
    int*  blocksums = offsets + C;
    int2* seg       = (int2*)(blocksums + 256);
    int*  node_list = (int*)(seg + C);

    hipMemsetAsync(counts, 0, (size_t)2 * C * sizeof(int), stream);

    cp_count<<<(n_nodes + 255) / 256, 256, 0, stream>>>(cmap, counts, n_nodes);

    int nb = (C + 255) / 256;
    cp_scanA<<<nb, 256, 0, stream>>>(counts, offsets, blocksums, C);
    cp_scanB<<<1, 256, 0, stream>>>(blocksums, nb);
    cp_scanC<<<nb, 256, 0, stream>>>(offsets, blocksums, counts, seg, C);

    cp_fill<<<(n_nodes + 255) / 256, 256, 0, stream>>>(cmap, offsets, cursor, node_list, n_nodes);

    cp_pool<<<(C + 3) / 4, 256, 0, stream>>>(x, h, seg, node_list, xp, hp, C);

    cp_pos<<<(C + 255) / 256, 256, 0, stream>>>(pos, sidx, pout, C);
}